// Round 4
// baseline (142.280 us; speedup 1.0000x reference)
//
#include <hip/hip_runtime.h>
#include <hip/hip_bf16.h>

#define NPTS 65536
#define MPTS 65536

typedef __attribute__((ext_vector_type(8))) short bf16x8;
typedef __attribute__((ext_vector_type(4))) float f32x4;

__device__ __forceinline__ float bflo(unsigned int u){ union{unsigned int i; float f;} v; v.i = u<<16; return v.f; }
__device__ __forceinline__ float bfhi(unsigned int u){ union{unsigned int i; float f;} v; v.i = u & 0xffff0000u; return v.f; }
__device__ __forceinline__ unsigned short f2bf(float f){
  union{float f; unsigned int i;} v; v.f=f;
  unsigned int r = v.i + 0x7fffu + ((v.i>>16)&1u);  // RNE
  return (unsigned short)(r>>16);
}
__device__ __forceinline__ unsigned int pk2f(float a, float b){
  float2 tf; tf.x = a; tf.y = b;
  union { __hip_bfloat162 h; unsigned int u; } c;
  c.h = __float22bfloat162_rn(tf);
  return c.u;
}
__device__ __forceinline__ float swz16(float x){
  return __int_as_float(__builtin_amdgcn_ds_swizzle(__float_as_int(x), 0x401F));
}
__device__ __forceinline__ float red4(f32x4 a){
  return fmaxf(fmaxf(a[0], a[1]), fmaxf(a[2], a[3]));
}

#define MFMA32(a,b,c) __builtin_amdgcn_mfma_f32_16x16x32_bf16((a),(b),(c),0,0,0)

// ---- pack_all: [0,1024) U-pack (LDS-transposed x); [1024,1028) W2F; [1028,1284) V ----
__global__ __launch_bounds__(256) void pack_all(
    const float* __restrict__ x,     // [64][N]
    const float* __restrict__ pos,   // [3][N]
    const float* __restrict__ sup,   // [3][M]
    const float* __restrict__ W1,    // [64][67]
    const float* __restrict__ b1,
    const float* __restrict__ W2,    // [128][64]
    unsigned short* __restrict__ U,  // [N][64] bf16
    unsigned short* __restrict__ W2F,
    float* __restrict__ V) {         // [M][64] fp32 (may be null)
  const int t = threadIdx.x;
  if (blockIdx.x >= 1028) {          // V image
    const int m = (blockIdx.x - 1028) * 256 + t;
    const float s0 = sup[m], s1 = sup[MPTS + m], s2 = sup[2*MPTS + m];
    #pragma unroll
    for (int cg = 0; cg < 16; ++cg) {
      const float* r0 = W1 + (size_t)(cg*4 + 0)*67 + 64;
      const float* r1 = W1 + (size_t)(cg*4 + 1)*67 + 64;
      const float* r2 = W1 + (size_t)(cg*4 + 2)*67 + 64;
      const float* r3 = W1 + (size_t)(cg*4 + 3)*67 + 64;
      float4 o;
      o.x = r0[0]*s0 + r0[1]*s1 + r0[2]*s2;
      o.y = r1[0]*s0 + r1[1]*s1 + r1[2]*s2;
      o.z = r2[0]*s0 + r2[1]*s1 + r2[2]*s2;
      o.w = r3[0]*s0 + r3[1]*s1 + r3[2]*s2;
      *(float4*)(V + (size_t)m*64 + cg*4) = o;
    }
    return;
  }
  if (blockIdx.x >= 1024) {          // W2 fragment image
    const int gg = (blockIdx.x - 1024) * 256 + t;
    if (gg < 1024) {
      const int g = gg >> 6, lane = gg & 63;
      const int q = lane >> 4, lr = lane & 15;
      const int kt = g >> 3, ot = g & 7;
      #pragma unroll
      for (int j = 0; j < 4; ++j)
        *(unsigned int*)&W2F[gg*8 + 2*j] =
            pk2f(W2[(ot*16 + lr)*64 + kt*32 + q*8 + 2*j],
                 W2[(ot*16 + lr)*64 + kt*32 + q*8 + 2*j + 1]);
    }
    return;
  }
  // ---- U-pack with LDS-transposed x/pos loads ----
  __shared__ float sx[67][65];
  const int n0 = blockIdx.x * 64;
  #pragma unroll
  for (int i = 0; i < 4; ++i) {
    const int lin = i*256 + t, r = lin >> 4, c4 = (lin & 15) * 4;
    const float4 v = *(const float4*)&x[(size_t)r * NPTS + n0 + c4];
    *(float4*)&sx[r][c4] = v;
  }
  if (t < 48) {
    const int lin = 1024 + t, r = lin >> 4, c4 = (lin & 15) * 4;
    const float4 v = *(const float4*)&pos[(size_t)(r - 64) * NPTS + n0 + c4];
    *(float4*)&sx[r][c4] = v;
  }

  const int lane = t & 63, w = t >> 6, quad = lane >> 4, lr = lane & 15;
  const int col = w * 16 + lr;
  const int n = n0 + col;

  bf16x8 wa[2][4], wt[4];
  #pragma unroll
  for (int kt = 0; kt < 2; ++kt)
    #pragma unroll
    for (int nt = 0; nt < 4; ++nt) {
      const float* r = W1 + (size_t)(nt*16 + lr)*67 + kt*32 + quad*8;
      const float4 a = *(const float4*)r;
      const float4 b = *(const float4*)(r + 4);
      union { unsigned int d[4]; bf16x8 v; } mk;
      mk.d[0] = pk2f(a.x, a.y); mk.d[1] = pk2f(a.z, a.w);
      mk.d[2] = pk2f(b.x, b.y); mk.d[3] = pk2f(b.z, b.w);
      wa[kt][nt] = mk.v;
    }
  #pragma unroll
  for (int nt = 0; nt < 4; ++nt) {
    union { unsigned int d[4]; bf16x8 v; } mk;
    mk.d[0] = 0u; mk.d[1] = 0u; mk.d[2] = 0u; mk.d[3] = 0u;
    if (quad == 0) {
      const float* r = W1 + (size_t)(nt*16 + lr)*67 + 64;
      mk.d[0] = pk2f(r[0], r[1]);
      mk.d[1] = (unsigned int)f2bf(r[2]);
    }
    wt[nt] = mk.v;
  }

  __syncthreads();

  const f32x4 fz = {0.f, 0.f, 0.f, 0.f};
  f32x4 acc[4] = {fz, fz, fz, fz};
  #pragma unroll
  for (int kt = 0; kt < 2; ++kt) {
    const int c0 = kt*32 + quad*8;
    union { unsigned int d[4]; bf16x8 v; } mk;
    #pragma unroll
    for (int i = 0; i < 4; ++i)
      mk.d[i] = pk2f(sx[c0 + 2*i][col], sx[c0 + 2*i + 1][col]);
    #pragma unroll
    for (int nt = 0; nt < 4; ++nt)
      acc[nt] = MFMA32(wa[kt][nt], mk.v, acc[nt]);
  }
  {
    union { unsigned int d[4]; bf16x8 v; } mk;
    mk.d[0] = pk2f(sx[64][col], sx[65][col]);
    mk.d[1] = (unsigned int)f2bf(sx[66][col]);
    mk.d[2] = 0u; mk.d[3] = 0u;
    #pragma unroll
    for (int nt = 0; nt < 4; ++nt)
      acc[nt] = MFMA32(wt[nt], mk.v, acc[nt]);
  }
  #pragma unroll
  for (int nt = 0; nt < 4; ++nt) {
    const float4 bb = *(const float4*)(b1 + nt*16 + quad*4);
    uint2 d;
    d.x = pk2f(acc[nt][0] + bb.x, acc[nt][1] + bb.y);
    d.y = pk2f(acc[nt][2] + bb.z, acc[nt][3] + bb.w);
    *(uint2*)(U + (size_t)n * 64 + nt*16 + quad*4) = d;
  }
}

// ---- main v5: 2-group pipeline, wave-private V LDS, batched xlane, no barrier ----
__global__ __launch_bounds__(256, 3) void pointnet_reg5(
    const unsigned short* __restrict__ U,    // [N][64] bf16
    const float* __restrict__ V,             // [M][64] fp32
    const unsigned short* __restrict__ W2F,
    const float* __restrict__ b2,
    const int* __restrict__ indices,         // [M][16]
    float* __restrict__ out) {               // [128][M]
  __shared__ float sv[32][68];               // pitch 68: 16B-aligned rows, conflict-free writes
  const int t = threadIdx.x;
  const int lane = t & 63, w = t >> 6, quad = lane >> 4, lr = lane & 15;
  const int mbase = blockIdx.x * 32;
  const int wbase = mbase + w * 8;

  // 1) index loads first (longest chain: idx -> gather -> pack)
  int idx[2][4];
  #pragma unroll
  for (int g = 0; g < 2; ++g)
    #pragma unroll
    for (int p = 0; p < 4; ++p)
      idx[g][p] = indices[(wbase + g*4 + p)*16 + lr];

  // 2) V loads (fill idx latency window); rows are wave-private
  const int vrow = w*8 + (lane >> 3), vcol = (lane & 7) * 8;
  const float* vg = &V[(size_t)(mbase + vrow) * 64 + vcol];
  const float4 vt0 = *(const float4*)(vg);
  const float4 vt1 = *(const float4*)(vg + 4);

  // 3) both gather batches issued up front (16x 16B in flight)
  uint4 ur0[4][2], ur1[4][2];
  #pragma unroll
  for (int p = 0; p < 4; ++p) {
    const size_t rowb = (size_t)idx[0][p] * 64;
    ur0[p][0] = *(const uint4*)(U + rowb + quad*8);
    ur0[p][1] = *(const uint4*)(U + rowb + 32 + quad*8);
  }
  #pragma unroll
  for (int p = 0; p < 4; ++p) {
    const size_t rowb = (size_t)idx[1][p] * 64;
    ur1[p][0] = *(const uint4*)(U + rowb + quad*8);
    ur1[p][1] = *(const uint4*)(U + rowb + 32 + quad*8);
  }

  // 4) V -> wave-private LDS (no __syncthreads anywhere)
  *(float4*)&sv[vrow][vcol]     = vt0;
  *(float4*)&sv[vrow][vcol + 4] = vt1;

  // 5) bias preload
  float bias[8];
  #pragma unroll
  for (int ot = 0; ot < 8; ++ot) bias[ot] = b2[ot*16 + lr];

  const f32x4 fz = {0.f, 0.f, 0.f, 0.f};
  const bf16x8* W2Fv = (const bf16x8*)W2F;

#define PN_GROUP(g, CUR)                                                        \
  {                                                                             \
    bf16x8 ah[4][2];                                                            \
    _Pragma("unroll")                                                           \
    for (int p = 0; p < 4; ++p) {                                               \
      const float* vr = &sv[w*8 + (g)*4 + p][quad*8];                           \
      const f32x4 v0 = *(const f32x4*)(vr);                                     \
      const f32x4 v1 = *(const f32x4*)(vr + 4);                                 \
      const f32x4 v2 = *(const f32x4*)(vr + 32);                                \
      const f32x4 v3 = *(const f32x4*)(vr + 36);                                \
      const float vv[16] = {v0[0],v0[1],v0[2],v0[3], v1[0],v1[1],v1[2],v1[3],   \
                            v2[0],v2[1],v2[2],v2[3], v3[0],v3[1],v3[2],v3[3]};  \
      _Pragma("unroll")                                                         \
      for (int kt = 0; kt < 2; ++kt) {                                          \
        const unsigned int uu[4] = {CUR[p][kt].x, CUR[p][kt].y,                 \
                                    CUR[p][kt].z, CUR[p][kt].w};                \
        union { unsigned int d[4]; bf16x8 v; } mk;                              \
        _Pragma("unroll")                                                       \
        for (int i = 0; i < 4; ++i) {                                           \
          const float lo = bflo(uu[i]) - vv[kt*8 + 2*i];                        \
          const float hi = bfhi(uu[i]) - vv[kt*8 + 2*i + 1];                    \
          mk.d[i] = pk2f(fmaxf(lo, 0.f), fmaxf(hi, 0.f));                       \
        }                                                                       \
        ah[p][kt] = mk.v;                                                       \
      }                                                                         \
    }                                                                           \
    _Pragma("unroll")                                                           \
    for (int ot = 0; ot < 8; ++ot) {                                            \
      const bf16x8 wb0 = W2Fv[(0*8 + ot)*64 + lane];                            \
      const bf16x8 wb1 = W2Fv[(1*8 + ot)*64 + lane];                            \
      f32x4 aA, aB;                                                             \
      aA = MFMA32(ah[0][0], wb0, fz); aA = MFMA32(ah[0][1], wb1, aA);           \
      aB = MFMA32(ah[1][0], wb0, fz); aB = MFMA32(ah[1][1], wb1, aB);           \
      float q0 = red4(aA);                                                      \
      aA = MFMA32(ah[2][0], wb0, fz); aA = MFMA32(ah[2][1], wb1, aA);           \
      float q1 = red4(aB);                                                      \
      aB = MFMA32(ah[3][0], wb0, fz); aB = MFMA32(ah[3][1], wb1, aB);           \
      float q2 = red4(aA);                                                      \
      float q3 = red4(aB);                                                      \
      float u0 = swz16(q0), u1 = swz16(q1), u2 = swz16(q2), u3 = swz16(q3);     \
      q0 = fmaxf(q0, u0); q1 = fmaxf(q1, u1);                                   \
      q2 = fmaxf(q2, u2); q3 = fmaxf(q3, u3);                                   \
      u0 = __shfl_xor(q0, 32); u1 = __shfl_xor(q1, 32);                         \
      u2 = __shfl_xor(q2, 32); u3 = __shfl_xor(q3, 32);                         \
      q0 = fmaxf(q0, u0); q1 = fmaxf(q1, u1);                                   \
      q2 = fmaxf(q2, u2); q3 = fmaxf(q3, u3);                                   \
      const float e = (quad & 1) ? ((quad & 2) ? q3 : q1)                       \
                                 : ((quad & 2) ? q2 : q0);                      \
      out[(size_t)(ot*16 + lr) * MPTS + wbase + (g)*4 + quad] = e + bias[ot];   \
    }                                                                           \
  }

  PN_GROUP(0, ur0)   // group-1 gathers remain in flight under this compute
  PN_GROUP(1, ur1)
#undef PN_GROUP
}

// ---- main v1 (middle path if workspace too small for V) ----
__global__ __launch_bounds__(256, 3) void pointnet_reg(
    const unsigned short* __restrict__ U,
    const float* __restrict__ sup,
    const float* __restrict__ W1,
    const unsigned short* __restrict__ W2F,
    const float* __restrict__ b2,
    const int* __restrict__ indices,
    float* __restrict__ out) {
  const int t = threadIdx.x;
  const int lane = t & 63, w = t >> 6, quad = lane >> 4, lr = lane & 15;
  const int wbase = blockIdx.x * 32 + w * 8;

  int idx[8];
  #pragma unroll
  for (int pt = 0; pt < 8; ++pt) idx[pt] = indices[(wbase + pt)*16 + lr];

  uint4 ur[8][2];
  #pragma unroll
  for (int pt = 0; pt < 8; ++pt)
    #pragma unroll
    for (int kt = 0; kt < 2; ++kt)
      ur[pt][kt] = *(const uint4*)(U + (size_t)idx[pt]*64 + kt*32 + quad*8);

  bf16x8 ah[8][2];
  #pragma unroll
  for (int kt = 0; kt < 2; ++kt) {
    float w1p[8][3];
    #pragma unroll
    for (int j = 0; j < 8; ++j) {
      const float* r = W1 + (size_t)(kt*32 + quad*8 + j)*67 + 64;
      w1p[j][0] = r[0]; w1p[j][1] = r[1]; w1p[j][2] = r[2];
    }
    #pragma unroll
    for (int pt = 0; pt < 8; ++pt) {
      const float s0 = sup[wbase + pt];
      const float s1 = sup[MPTS + wbase + pt];
      const float s2 = sup[2*MPTS + wbase + pt];
      const unsigned int uu[4] = {ur[pt][kt].x, ur[pt][kt].y, ur[pt][kt].z, ur[pt][kt].w};
      union { unsigned int d[4]; bf16x8 v; } mk;
      #pragma unroll
      for (int i = 0; i < 4; ++i) {
        const float vl = w1p[2*i][0]*s0 + w1p[2*i][1]*s1 + w1p[2*i][2]*s2;
        const float vh = w1p[2*i+1][0]*s0 + w1p[2*i+1][1]*s1 + w1p[2*i+1][2]*s2;
        const float hl = fmaxf(bflo(uu[i]) - vl, 0.f);
        const float hh = fmaxf(bfhi(uu[i]) - vh, 0.f);
        mk.d[i] = pk2f(hl, hh);
      }
      ah[pt][kt] = mk.v;
    }
  }

  const f32x4 fz = {0.f, 0.f, 0.f, 0.f};
  #pragma unroll
  for (int ot = 0; ot < 8; ++ot) {
    const bf16x8 wb0 = ((const bf16x8*)W2F)[(0*8 + ot)*64 + lane];
    const bf16x8 wb1 = ((const bf16x8*)W2F)[(1*8 + ot)*64 + lane];
    float vm[8];
    #pragma unroll
    for (int pt = 0; pt < 8; ++pt) {
      f32x4 a2 = MFMA32(ah[pt][0], wb0, fz);
      a2 = MFMA32(ah[pt][1], wb1, a2);
      float v = fmaxf(fmaxf(a2[0], a2[1]), fmaxf(a2[2], a2[3]));
      v = fmaxf(v, __shfl_xor(v, 16));
      v = fmaxf(v, __shfl_xor(v, 32));
      vm[pt] = v;
    }
    const int o = ot*16 + lr;
    const float bb = b2[o];
    const float va = (quad & 1) ? ((quad & 2) ? vm[3] : vm[1])
                                : ((quad & 2) ? vm[2] : vm[0]);
    const float vb = (quad & 1) ? ((quad & 2) ? vm[7] : vm[5])
                                : ((quad & 2) ? vm[6] : vm[4]);
    out[(size_t)o * MPTS + wbase + quad] = va + bb;
    out[(size_t)o * MPTS + wbase + 4 + quad] = vb + bb;
  }
}

// ---- fallback (ws too small): direct fp32 kernel, known-correct ----
__global__ __launch_bounds__(256) void pointnet_fallback(
    const float* __restrict__ x, const float* __restrict__ pos,
    const float* __restrict__ sup,
    const float* __restrict__ W1, const float* __restrict__ b1,
    const float* __restrict__ W2, const float* __restrict__ b2,
    const int* __restrict__ indices, float* __restrict__ out) {
  __shared__ float sfeat[16][68];
  __shared__ float shid[16][64];
  __shared__ float smax[4][128];
  __shared__ int sidx[16];
  const int t = threadIdx.x;
  const int m = blockIdx.x;
  if (t < 16) sidx[t] = indices[m*16 + t];
  const float sup0 = sup[m], sup1 = sup[MPTS + m], sup2 = sup[2*MPTS + m];
  __syncthreads();
  for (int u = t; u < 16*17; u += 256) {
    const int k = u / 17, c4 = (u - k*17) * 4;
    const int idx = sidx[k];
    float4 wv;
    if (c4 < 64) {
      wv.x = x[(size_t)(c4+0)*NPTS + idx]; wv.y = x[(size_t)(c4+1)*NPTS + idx];
      wv.z = x[(size_t)(c4+2)*NPTS + idx]; wv.w = x[(size_t)(c4+3)*NPTS + idx];
    } else {
      wv.x = pos[idx] - sup0; wv.y = pos[NPTS + idx] - sup1;
      wv.z = pos[2*NPTS + idx] - sup2; wv.w = 0.f;
    }
    *(float4*)&sfeat[k][c4] = wv;
  }
  const int h = t & 63, kg = t >> 6;
  float w1r[68];
  #pragma unroll
  for (int c = 0; c < 67; ++c) w1r[c] = W1[h*67 + c];
  w1r[67] = 0.f;
  const float bias1 = b1[h];
  __syncthreads();
  #pragma unroll
  for (int j = 0; j < 4; ++j) {
    const int k = kg*4 + j;
    float a = bias1;
    const float4* rr = (const float4*)sfeat[k];
    #pragma unroll
    for (int qq = 0; qq < 17; ++qq) {
      const float4 v = rr[qq];
      a += w1r[qq*4+0]*v.x + w1r[qq*4+1]*v.y + w1r[qq*4+2]*v.z + w1r[qq*4+3]*v.w;
    }
    shid[k][h] = fmaxf(a, 0.f);
  }
  const int ow = t & 63;
  float w2a[64], w2b[64];
  #pragma unroll
  for (int hh = 0; hh < 64; ++hh) { w2a[hh] = W2[ow*64 + hh]; w2b[hh] = W2[(ow+64)*64 + hh]; }
  __syncthreads();
  float mxa = -3.0e38f, mxb = -3.0e38f;
  #pragma unroll
  for (int j = 0; j < 4; ++j) {
    const int k = kg*4 + j;
    const float4* hr = (const float4*)shid[k];
    float pa = 0.f, pb = 0.f;
    #pragma unroll
    for (int qq = 0; qq < 16; ++qq) {
      const float4 v = hr[qq];
      pa += w2a[qq*4+0]*v.x + w2a[qq*4+1]*v.y + w2a[qq*4+2]*v.z + w2a[qq*4+3]*v.w;
      pb += w2b[qq*4+0]*v.x + w2b[qq*4+1]*v.y + w2b[qq*4+2]*v.z + w2b[qq*4+3]*v.w;
    }
    mxa = fmaxf(mxa, pa); mxb = fmaxf(mxb, pb);
  }
  smax[kg][ow] = mxa; smax[kg][64 + ow] = mxb;
  __syncthreads();
  if (t < 128) {
    out[(size_t)t * MPTS + m] =
        fmaxf(fmaxf(smax[0][t], smax[1][t]), fmaxf(smax[2][t], smax[3][t])) + b2[t];
  }
}

extern "C" void kernel_launch(void* const* d_in, const int* in_sizes, int n_in,
                              void* d_out, int out_size, void* d_ws, size_t ws_size,
                              hipStream_t stream) {
  const float* x   = (const float*)d_in[0];
  const float* pos = (const float*)d_in[1];
  const float* sup = (const float*)d_in[2];
  const float* W1  = (const float*)d_in[3];
  const float* b1  = (const float*)d_in[4];
  const float* W2  = (const float*)d_in[5];
  const float* b2  = (const float*)d_in[6];
  const int* indices = (const int*)d_in[7];
  float* out = (float*)d_out;

  const size_t U_BYTES   = (size_t)NPTS * 64 * 2;     // 8,388,608
  const size_t W2F_BYTES = 16 * 64 * 8 * 2;           // 16,384
  const size_t V_BYTES   = (size_t)MPTS * 64 * 4;     // 16,777,216
  if (ws_size >= U_BYTES + W2F_BYTES + V_BYTES) {
    unsigned short* U   = (unsigned short*)d_ws;
    unsigned short* W2F = (unsigned short*)((char*)d_ws + U_BYTES);
    float* V            = (float*)((char*)d_ws + U_BYTES + W2F_BYTES);
    pack_all<<<1284, 256, 0, stream>>>(x, pos, sup, W1, b1, W2, U, W2F, V);
    pointnet_reg5<<<MPTS/32, 256, 0, stream>>>(U, V, W2F, b2, indices, out);
  } else if (ws_size >= U_BYTES + W2F_BYTES) {
    unsigned short* U   = (unsigned short*)d_ws;
    unsigned short* W2F = (unsigned short*)((char*)d_ws + U_BYTES);
    pack_all<<<1028, 256, 0, stream>>>(x, pos, sup, W1, b1, W2, U, W2F, nullptr);
    pointnet_reg<<<MPTS/32, 256, 0, stream>>>(U, sup, W1, W2F, b2, indices, out);
  } else {
    pointnet_fallback<<<MPTS, 256, 0, stream>>>(x, pos, sup, W1, b1, W2, b2, indices, out);
  }
}

// Round 5
// 140.371 us; speedup vs baseline: 1.0136x; 1.0136x over previous
//
#include <hip/hip_runtime.h>
#include <hip/hip_bf16.h>

#define NPTS 65536
#define MPTS 65536

typedef __attribute__((ext_vector_type(8))) short bf16x8;
typedef __attribute__((ext_vector_type(4))) float f32x4;

__device__ __forceinline__ float bflo(unsigned int u){ union{unsigned int i; float f;} v; v.i = u<<16; return v.f; }
__device__ __forceinline__ float bfhi(unsigned int u){ union{unsigned int i; float f;} v; v.i = u & 0xffff0000u; return v.f; }
__device__ __forceinline__ unsigned short f2bf(float f){
  union{float f; unsigned int i;} v; v.f=f;
  unsigned int r = v.i + 0x7fffu + ((v.i>>16)&1u);  // RNE
  return (unsigned short)(r>>16);
}
__device__ __forceinline__ unsigned int pk2f(float a, float b){
  float2 tf; tf.x = a; tf.y = b;
  union { __hip_bfloat162 h; unsigned int u; } c;
  c.h = __float22bfloat162_rn(tf);
  return c.u;
}
__device__ __forceinline__ float swz16(float x){
  return __int_as_float(__builtin_amdgcn_ds_swizzle(__float_as_int(x), 0x401F));
}
__device__ __forceinline__ float red4(f32x4 a){
  return fmaxf(fmaxf(a[0], a[1]), fmaxf(a[2], a[3]));
}

#define MFMA32(a,b,c) __builtin_amdgcn_mfma_f32_16x16x32_bf16((a),(b),(c),0,0,0)

// ---- pack_all: [0,1024) U-pack (LDS-transposed x); [1024,1028) W2F; [1028,1284) V ----
__global__ __launch_bounds__(256) void pack_all(
    const float* __restrict__ x,     // [64][N]
    const float* __restrict__ pos,   // [3][N]
    const float* __restrict__ sup,   // [3][M]
    const float* __restrict__ W1,    // [64][67]
    const float* __restrict__ b1,
    const float* __restrict__ W2,    // [128][64]
    unsigned short* __restrict__ U,  // [N][64] bf16
    unsigned short* __restrict__ W2F,
    float* __restrict__ V) {         // [M][64] fp32 (may be null)
  const int t = threadIdx.x;
  if (blockIdx.x >= 1028) {          // V image
    const int m = (blockIdx.x - 1028) * 256 + t;
    const float s0 = sup[m], s1 = sup[MPTS + m], s2 = sup[2*MPTS + m];
    #pragma unroll
    for (int cg = 0; cg < 16; ++cg) {
      const float* r0 = W1 + (size_t)(cg*4 + 0)*67 + 64;
      const float* r1 = W1 + (size_t)(cg*4 + 1)*67 + 64;
      const float* r2 = W1 + (size_t)(cg*4 + 2)*67 + 64;
      const float* r3 = W1 + (size_t)(cg*4 + 3)*67 + 64;
      float4 o;
      o.x = r0[0]*s0 + r0[1]*s1 + r0[2]*s2;
      o.y = r1[0]*s0 + r1[1]*s1 + r1[2]*s2;
      o.z = r2[0]*s0 + r2[1]*s1 + r2[2]*s2;
      o.w = r3[0]*s0 + r3[1]*s1 + r3[2]*s2;
      *(float4*)(V + (size_t)m*64 + cg*4) = o;
    }
    return;
  }
  if (blockIdx.x >= 1024) {          // W2 fragment image
    const int gg = (blockIdx.x - 1024) * 256 + t;
    if (gg < 1024) {
      const int g = gg >> 6, lane = gg & 63;
      const int q = lane >> 4, lr = lane & 15;
      const int kt = g >> 3, ot = g & 7;
      #pragma unroll
      for (int j = 0; j < 4; ++j)
        *(unsigned int*)&W2F[gg*8 + 2*j] =
            pk2f(W2[(ot*16 + lr)*64 + kt*32 + q*8 + 2*j],
                 W2[(ot*16 + lr)*64 + kt*32 + q*8 + 2*j + 1]);
    }
    return;
  }
  // ---- U-pack with LDS-transposed x/pos loads ----
  __shared__ float sx[67][65];
  const int n0 = blockIdx.x * 64;
  #pragma unroll
  for (int i = 0; i < 4; ++i) {
    const int lin = i*256 + t, r = lin >> 4, c4 = (lin & 15) * 4;
    const float4 v = *(const float4*)&x[(size_t)r * NPTS + n0 + c4];
    *(float4*)&sx[r][c4] = v;
  }
  if (t < 48) {
    const int lin = 1024 + t, r = lin >> 4, c4 = (lin & 15) * 4;
    const float4 v = *(const float4*)&pos[(size_t)(r - 64) * NPTS + n0 + c4];
    *(float4*)&sx[r][c4] = v;
  }

  const int lane = t & 63, w = t >> 6, quad = lane >> 4, lr = lane & 15;
  const int col = w * 16 + lr;
  const int n = n0 + col;

  bf16x8 wa[2][4], wt[4];
  #pragma unroll
  for (int kt = 0; kt < 2; ++kt)
    #pragma unroll
    for (int nt = 0; nt < 4; ++nt) {
      const float* r = W1 + (size_t)(nt*16 + lr)*67 + kt*32 + quad*8;
      const float4 a = *(const float4*)r;
      const float4 b = *(const float4*)(r + 4);
      union { unsigned int d[4]; bf16x8 v; } mk;
      mk.d[0] = pk2f(a.x, a.y); mk.d[1] = pk2f(a.z, a.w);
      mk.d[2] = pk2f(b.x, b.y); mk.d[3] = pk2f(b.z, b.w);
      wa[kt][nt] = mk.v;
    }
  #pragma unroll
  for (int nt = 0; nt < 4; ++nt) {
    union { unsigned int d[4]; bf16x8 v; } mk;
    mk.d[0] = 0u; mk.d[1] = 0u; mk.d[2] = 0u; mk.d[3] = 0u;
    if (quad == 0) {
      const float* r = W1 + (size_t)(nt*16 + lr)*67 + 64;
      mk.d[0] = pk2f(r[0], r[1]);
      mk.d[1] = (unsigned int)f2bf(r[2]);
    }
    wt[nt] = mk.v;
  }

  __syncthreads();

  const f32x4 fz = {0.f, 0.f, 0.f, 0.f};
  f32x4 acc[4] = {fz, fz, fz, fz};
  #pragma unroll
  for (int kt = 0; kt < 2; ++kt) {
    const int c0 = kt*32 + quad*8;
    union { unsigned int d[4]; bf16x8 v; } mk;
    #pragma unroll
    for (int i = 0; i < 4; ++i)
      mk.d[i] = pk2f(sx[c0 + 2*i][col], sx[c0 + 2*i + 1][col]);
    #pragma unroll
    for (int nt = 0; nt < 4; ++nt)
      acc[nt] = MFMA32(wa[kt][nt], mk.v, acc[nt]);
  }
  {
    union { unsigned int d[4]; bf16x8 v; } mk;
    mk.d[0] = pk2f(sx[64][col], sx[65][col]);
    mk.d[1] = (unsigned int)f2bf(sx[66][col]);
    mk.d[2] = 0u; mk.d[3] = 0u;
    #pragma unroll
    for (int nt = 0; nt < 4; ++nt)
      acc[nt] = MFMA32(wt[nt], mk.v, acc[nt]);
  }
  #pragma unroll
  for (int nt = 0; nt < 4; ++nt) {
    const float4 bb = *(const float4*)(b1 + nt*16 + quad*4);
    uint2 d;
    d.x = pk2f(acc[nt][0] + bb.x, acc[nt][1] + bb.y);
    d.y = pk2f(acc[nt][2] + bb.z, acc[nt][3] + bb.w);
    *(uint2*)(U + (size_t)n * 64 + nt*16 + quad*4) = d;
  }
}

// ---- main v6: 2-tile/block software pipeline, wave-private V LDS, no barriers,
//      full-vm float2 stores (32B/row/wave), batched cross-lane reduction ----
__global__ __launch_bounds__(256, 2) void pointnet_reg6(
    const unsigned short* __restrict__ U,    // [N][64] bf16
    const float* __restrict__ V,             // [M][64] fp32
    const unsigned short* __restrict__ W2F,
    const float* __restrict__ b2,
    const int* __restrict__ indices,         // [M][16]
    float* __restrict__ out) {               // [128][M]
  __shared__ float sv[64][68];               // 2 tiles x 32 rows, pitch 68 (16B-aligned)
  const int t = threadIdx.x;
  const int lane = t & 63, w = t >> 6, quad = lane >> 4, lr = lane & 15;
  const int mb0 = blockIdx.x * 64;           // tile0 rows mb0.., tile1 rows mb0+32..
  const int wb0 = mb0 + w * 8;
  const int wb1 = mb0 + 32 + w * 8;

  // ---- tile0 loads ----
  int idx0[8];
  #pragma unroll
  for (int pt = 0; pt < 8; ++pt) idx0[pt] = indices[(wb0 + pt)*16 + lr];
  const int vrow = w*8 + (lane >> 3), vcol = (lane & 7) * 8;
  const float* vg0 = &V[(size_t)(mb0 + vrow) * 64 + vcol];
  const float4 va0 = *(const float4*)(vg0);
  const float4 va1 = *(const float4*)(vg0 + 4);
  uint4 ur0[8][2];
  #pragma unroll
  for (int pt = 0; pt < 8; ++pt) {
    const size_t rb = (size_t)idx0[pt] * 64;
    ur0[pt][0] = *(const uint4*)(U + rb + quad*8);
    ur0[pt][1] = *(const uint4*)(U + rb + 32 + quad*8);
  }
  *(float4*)&sv[vrow][vcol]     = va0;   // wave-private rows: no barrier needed
  *(float4*)&sv[vrow][vcol + 4] = va1;

  // ---- tile1 loads (all issued BEFORE tile0 compute; stay in flight under it) ----
  int idx1[8];
  #pragma unroll
  for (int pt = 0; pt < 8; ++pt) idx1[pt] = indices[(wb1 + pt)*16 + lr];
  const float* vg1 = &V[(size_t)(mb0 + 32 + vrow) * 64 + vcol];
  const float4 vb0 = *(const float4*)(vg1);
  const float4 vb1 = *(const float4*)(vg1 + 4);
  uint4 ur1[8][2];
  #pragma unroll
  for (int pt = 0; pt < 8; ++pt) {
    const size_t rb = (size_t)idx1[pt] * 64;
    ur1[pt][0] = *(const uint4*)(U + rb + quad*8);
    ur1[pt][1] = *(const uint4*)(U + rb + 32 + quad*8);
  }
  *(float4*)&sv[32 + vrow][vcol]     = vb0;
  *(float4*)&sv[32 + vrow][vcol + 4] = vb1;

  // pin the issue order: tile1 loads above must not sink below tile0 compute
  __builtin_amdgcn_sched_barrier(0);

  float bias[8];
  #pragma unroll
  for (int ot = 0; ot < 8; ++ot) bias[ot] = b2[ot*16 + lr];

  const f32x4 fz = {0.f, 0.f, 0.f, 0.f};
  const bf16x8* W2Fv = (const bf16x8*)W2F;

#define PN_TILE(TB, UR, WB)                                                     \
  {                                                                             \
    bf16x8 ah[8][2];                                                            \
    _Pragma("unroll")                                                           \
    for (int pt = 0; pt < 8; ++pt) {                                            \
      const float* vr = &sv[(TB) + w*8 + pt][quad*8];                           \
      const f32x4 v0 = *(const f32x4*)(vr);                                     \
      const f32x4 v1 = *(const f32x4*)(vr + 4);                                 \
      const f32x4 v2 = *(const f32x4*)(vr + 32);                                \
      const f32x4 v3 = *(const f32x4*)(vr + 36);                                \
      const float vv[16] = {v0[0],v0[1],v0[2],v0[3], v1[0],v1[1],v1[2],v1[3],   \
                            v2[0],v2[1],v2[2],v2[3], v3[0],v3[1],v3[2],v3[3]};  \
      _Pragma("unroll")                                                         \
      for (int kt = 0; kt < 2; ++kt) {                                          \
        const unsigned int uu[4] = {UR[pt][kt].x, UR[pt][kt].y,                 \
                                    UR[pt][kt].z, UR[pt][kt].w};                \
        union { unsigned int d[4]; bf16x8 v; } mk;                              \
        _Pragma("unroll")                                                       \
        for (int i = 0; i < 4; ++i) {                                           \
          const float lo = bflo(uu[i]) - vv[kt*8 + 2*i];                        \
          const float hi = bfhi(uu[i]) - vv[kt*8 + 2*i + 1];                    \
          mk.d[i] = pk2f(fmaxf(lo, 0.f), fmaxf(hi, 0.f));                       \
        }                                                                       \
        ah[pt][kt] = mk.v;                                                      \
      }                                                                         \
    }                                                                           \
    _Pragma("unroll")                                                           \
    for (int ot = 0; ot < 8; ++ot) {                                            \
      const bf16x8 f0 = W2Fv[(0*8 + ot)*64 + lane];                             \
      const bf16x8 f1 = W2Fv[(1*8 + ot)*64 + lane];                             \
      float q[8];                                                               \
      __builtin_amdgcn_s_setprio(1);                                            \
      _Pragma("unroll")                                                         \
      for (int pt = 0; pt < 8; ++pt) {                                          \
        f32x4 a2 = MFMA32(ah[pt][0], f0, fz);                                   \
        a2 = MFMA32(ah[pt][1], f1, a2);                                         \
        q[pt] = red4(a2);                                                       \
      }                                                                         \
      __builtin_amdgcn_s_setprio(0);                                            \
      float u[8];                                                               \
      _Pragma("unroll")                                                         \
      for (int pt = 0; pt < 8; ++pt) u[pt] = swz16(q[pt]);                      \
      _Pragma("unroll")                                                         \
      for (int pt = 0; pt < 8; ++pt) q[pt] = fmaxf(q[pt], u[pt]);               \
      _Pragma("unroll")                                                         \
      for (int pt = 0; pt < 8; ++pt) u[pt] = __shfl_xor(q[pt], 32);             \
      _Pragma("unroll")                                                         \
      for (int pt = 0; pt < 8; ++pt) q[pt] = fmaxf(q[pt], u[pt]);               \
      const int o = ot*16 + lr;                                                 \
      const float e0 = (quad & 1) ? ((quad & 2) ? q[6] : q[2])                  \
                                  : ((quad & 2) ? q[4] : q[0]);                 \
      const float e1 = (quad & 1) ? ((quad & 2) ? q[7] : q[3])                  \
                                  : ((quad & 2) ? q[5] : q[1]);                 \
      float2 st; st.x = e0 + bias[ot]; st.y = e1 + bias[ot];                    \
      *(float2*)&out[(size_t)o * MPTS + (WB) + 2*quad] = st;                    \
    }                                                                           \
  }

  PN_TILE(0,  ur0, wb0)   // tile1 gathers remain in flight under this compute
  PN_TILE(32, ur1, wb1)
#undef PN_TILE
}

// ---- main v1 (middle path if workspace too small for V) ----
__global__ __launch_bounds__(256, 3) void pointnet_reg(
    const unsigned short* __restrict__ U,
    const float* __restrict__ sup,
    const float* __restrict__ W1,
    const unsigned short* __restrict__ W2F,
    const float* __restrict__ b2,
    const int* __restrict__ indices,
    float* __restrict__ out) {
  const int t = threadIdx.x;
  const int lane = t & 63, w = t >> 6, quad = lane >> 4, lr = lane & 15;
  const int wbase = blockIdx.x * 32 + w * 8;

  int idx[8];
  #pragma unroll
  for (int pt = 0; pt < 8; ++pt) idx[pt] = indices[(wbase + pt)*16 + lr];

  uint4 ur[8][2];
  #pragma unroll
  for (int pt = 0; pt < 8; ++pt)
    #pragma unroll
    for (int kt = 0; kt < 2; ++kt)
      ur[pt][kt] = *(const uint4*)(U + (size_t)idx[pt]*64 + kt*32 + quad*8);

  bf16x8 ah[8][2];
  #pragma unroll
  for (int kt = 0; kt < 2; ++kt) {
    float w1p[8][3];
    #pragma unroll
    for (int j = 0; j < 8; ++j) {
      const float* r = W1 + (size_t)(kt*32 + quad*8 + j)*67 + 64;
      w1p[j][0] = r[0]; w1p[j][1] = r[1]; w1p[j][2] = r[2];
    }
    #pragma unroll
    for (int pt = 0; pt < 8; ++pt) {
      const float s0 = sup[wbase + pt];
      const float s1 = sup[MPTS + wbase + pt];
      const float s2 = sup[2*MPTS + wbase + pt];
      const unsigned int uu[4] = {ur[pt][kt].x, ur[pt][kt].y, ur[pt][kt].z, ur[pt][kt].w};
      union { unsigned int d[4]; bf16x8 v; } mk;
      #pragma unroll
      for (int i = 0; i < 4; ++i) {
        const float vl = w1p[2*i][0]*s0 + w1p[2*i][1]*s1 + w1p[2*i][2]*s2;
        const float vh = w1p[2*i+1][0]*s0 + w1p[2*i+1][1]*s1 + w1p[2*i+1][2]*s2;
        const float hl = fmaxf(bflo(uu[i]) - vl, 0.f);
        const float hh = fmaxf(bfhi(uu[i]) - vh, 0.f);
        mk.d[i] = pk2f(hl, hh);
      }
      ah[pt][kt] = mk.v;
    }
  }

  const f32x4 fz = {0.f, 0.f, 0.f, 0.f};
  #pragma unroll
  for (int ot = 0; ot < 8; ++ot) {
    const bf16x8 wb0 = ((const bf16x8*)W2F)[(0*8 + ot)*64 + lane];
    const bf16x8 wb1 = ((const bf16x8*)W2F)[(1*8 + ot)*64 + lane];
    float vm[8];
    #pragma unroll
    for (int pt = 0; pt < 8; ++pt) {
      f32x4 a2 = MFMA32(ah[pt][0], wb0, fz);
      a2 = MFMA32(ah[pt][1], wb1, a2);
      float v = fmaxf(fmaxf(a2[0], a2[1]), fmaxf(a2[2], a2[3]));
      v = fmaxf(v, __shfl_xor(v, 16));
      v = fmaxf(v, __shfl_xor(v, 32));
      vm[pt] = v;
    }
    const int o = ot*16 + lr;
    const float bb = b2[o];
    const float va = (quad & 1) ? ((quad & 2) ? vm[3] : vm[1])
                                : ((quad & 2) ? vm[2] : vm[0]);
    const float vb = (quad & 1) ? ((quad & 2) ? vm[7] : vm[5])
                                : ((quad & 2) ? vm[6] : vm[4]);
    out[(size_t)o * MPTS + wbase + quad] = va + bb;
    out[(size_t)o * MPTS + wbase + 4 + quad] = vb + bb;
  }
}

// ---- fallback (ws too small): direct fp32 kernel, known-correct ----
__global__ __launch_bounds__(256) void pointnet_fallback(
    const float* __restrict__ x, const float* __restrict__ pos,
    const float* __restrict__ sup,
    const float* __restrict__ W1, const float* __restrict__ b1,
    const float* __restrict__ W2, const float* __restrict__ b2,
    const int* __restrict__ indices, float* __restrict__ out) {
  __shared__ float sfeat[16][68];
  __shared__ float shid[16][64];
  __shared__ float smax[4][128];
  __shared__ int sidx[16];
  const int t = threadIdx.x;
  const int m = blockIdx.x;
  if (t < 16) sidx[t] = indices[m*16 + t];
  const float sup0 = sup[m], sup1 = sup[MPTS + m], sup2 = sup[2*MPTS + m];
  __syncthreads();
  for (int u = t; u < 16*17; u += 256) {
    const int k = u / 17, c4 = (u - k*17) * 4;
    const int idx = sidx[k];
    float4 wv;
    if (c4 < 64) {
      wv.x = x[(size_t)(c4+0)*NPTS + idx]; wv.y = x[(size_t)(c4+1)*NPTS + idx];
      wv.z = x[(size_t)(c4+2)*NPTS + idx]; wv.w = x[(size_t)(c4+3)*NPTS + idx];
    } else {
      wv.x = pos[idx] - sup0; wv.y = pos[NPTS + idx] - sup1;
      wv.z = pos[2*NPTS + idx] - sup2; wv.w = 0.f;
    }
    *(float4*)&sfeat[k][c4] = wv;
  }
  const int h = t & 63, kg = t >> 6;
  float w1r[68];
  #pragma unroll
  for (int c = 0; c < 67; ++c) w1r[c] = W1[h*67 + c];
  w1r[67] = 0.f;
  const float bias1 = b1[h];
  __syncthreads();
  #pragma unroll
  for (int j = 0; j < 4; ++j) {
    const int k = kg*4 + j;
    float a = bias1;
    const float4* rr = (const float4*)sfeat[k];
    #pragma unroll
    for (int qq = 0; qq < 17; ++qq) {
      const float4 v = rr[qq];
      a += w1r[qq*4+0]*v.x + w1r[qq*4+1]*v.y + w1r[qq*4+2]*v.z + w1r[qq*4+3]*v.w;
    }
    shid[k][h] = fmaxf(a, 0.f);
  }
  const int ow = t & 63;
  float w2a[64], w2b[64];
  #pragma unroll
  for (int hh = 0; hh < 64; ++hh) { w2a[hh] = W2[ow*64 + hh]; w2b[hh] = W2[(ow+64)*64 + hh]; }
  __syncthreads();
  float mxa = -3.0e38f, mxb = -3.0e38f;
  #pragma unroll
  for (int j = 0; j < 4; ++j) {
    const int k = kg*4 + j;
    const float4* hr = (const float4*)shid[k];
    float pa = 0.f, pb = 0.f;
    #pragma unroll
    for (int qq = 0; qq < 16; ++qq) {
      const float4 v = hr[qq];
      pa += w2a[qq*4+0]*v.x + w2a[qq*4+1]*v.y + w2a[qq*4+2]*v.z + w2a[qq*4+3]*v.w;
      pb += w2b[qq*4+0]*v.x + w2b[qq*4+1]*v.y + w2b[qq*4+2]*v.z + w2b[qq*4+3]*v.w;
    }
    mxa = fmaxf(mxa, pa); mxb = fmaxf(mxb, pb);
  }
  smax[kg][ow] = mxa; smax[kg][64 + ow] = mxb;
  __syncthreads();
  if (t < 128) {
    out[(size_t)t * MPTS + m] =
        fmaxf(fmaxf(smax[0][t], smax[1][t]), fmaxf(smax[2][t], smax[3][t])) + b2[t];
  }
}

extern "C" void kernel_launch(void* const* d_in, const int* in_sizes, int n_in,
                              void* d_out, int out_size, void* d_ws, size_t ws_size,
                              hipStream_t stream) {
  const float* x   = (const float*)d_in[0];
  const float* pos = (const float*)d_in[1];
  const float* sup = (const float*)d_in[2];
  const float* W1  = (const float*)d_in[3];
  const float* b1  = (const float*)d_in[4];
  const float* W2  = (const float*)d_in[5];
  const float* b2  = (const float*)d_in[6];
  const int* indices = (const int*)d_in[7];
  float* out = (float*)d_out;

  const size_t U_BYTES   = (size_t)NPTS * 64 * 2;     // 8,388,608
  const size_t W2F_BYTES = 16 * 64 * 8 * 2;           // 16,384
  const size_t V_BYTES   = (size_t)MPTS * 64 * 4;     // 16,777,216
  if (ws_size >= U_BYTES + W2F_BYTES + V_BYTES) {
    unsigned short* U   = (unsigned short*)d_ws;
    unsigned short* W2F = (unsigned short*)((char*)d_ws + U_BYTES);
    float* V            = (float*)((char*)d_ws + U_BYTES + W2F_BYTES);
    pack_all<<<1284, 256, 0, stream>>>(x, pos, sup, W1, b1, W2, U, W2F, V);
    pointnet_reg6<<<MPTS/64, 256, 0, stream>>>(U, V, W2F, b2, indices, out);
  } else if (ws_size >= U_BYTES + W2F_BYTES) {
    unsigned short* U   = (unsigned short*)d_ws;
    unsigned short* W2F = (unsigned short*)((char*)d_ws + U_BYTES);
    pack_all<<<1028, 256, 0, stream>>>(x, pos, sup, W1, b1, W2, U, W2F, nullptr);
    pointnet_reg<<<MPTS/32, 256, 0, stream>>>(U, sup, W1, W2F, b2, indices, out);
  } else {
    pointnet_fallback<<<MPTS, 256, 0, stream>>>(x, pos, sup, W1, b1, W2, b2, indices, out);
  }
}

// Round 6
// 135.958 us; speedup vs baseline: 1.0465x; 1.0325x over previous
//
#include <hip/hip_runtime.h>
#include <hip/hip_bf16.h>

#define NPTS 65536
#define MPTS 65536

typedef __attribute__((ext_vector_type(8))) short bf16x8;
typedef __attribute__((ext_vector_type(4))) float f32x4;

__device__ __forceinline__ float bflo(unsigned int u){ union{unsigned int i; float f;} v; v.i = u<<16; return v.f; }
__device__ __forceinline__ float bfhi(unsigned int u){ union{unsigned int i; float f;} v; v.i = u & 0xffff0000u; return v.f; }
__device__ __forceinline__ unsigned short f2bf(float f){
  union{float f; unsigned int i;} v; v.f=f;
  unsigned int r = v.i + 0x7fffu + ((v.i>>16)&1u);  // RNE
  return (unsigned short)(r>>16);
}
__device__ __forceinline__ unsigned int pk2f(float a, float b){
  float2 tf; tf.x = a; tf.y = b;
  union { __hip_bfloat162 h; unsigned int u; } c;
  c.h = __float22bfloat162_rn(tf);
  return c.u;
}
__device__ __forceinline__ float swz16(float x){
  return __int_as_float(__builtin_amdgcn_ds_swizzle(__float_as_int(x), 0x401F));
}
__device__ __forceinline__ float red4(f32x4 a){
  return fmaxf(fmaxf(a[0], a[1]), fmaxf(a[2], a[3]));
}

#define MFMA32(a,b,c) __builtin_amdgcn_mfma_f32_16x16x32_bf16((a),(b),(c),0,0,0)

// ---- pack_all: [0,1024) U-pack (LDS-transposed x); [1024,1028) W2F; [1028,1284) V ----
__global__ __launch_bounds__(256) void pack_all(
    const float* __restrict__ x,     // [64][N]
    const float* __restrict__ pos,   // [3][N]
    const float* __restrict__ sup,   // [3][M]
    const float* __restrict__ W1,    // [64][67]
    const float* __restrict__ b1,
    const float* __restrict__ W2,    // [128][64]
    unsigned short* __restrict__ U,  // [N][64] bf16
    unsigned short* __restrict__ W2F,
    float* __restrict__ V) {         // [M][64] fp32 (may be null)
  const int t = threadIdx.x;
  if (blockIdx.x >= 1028) {          // V image
    const int m = (blockIdx.x - 1028) * 256 + t;
    const float s0 = sup[m], s1 = sup[MPTS + m], s2 = sup[2*MPTS + m];
    #pragma unroll
    for (int cg = 0; cg < 16; ++cg) {
      const float* r0 = W1 + (size_t)(cg*4 + 0)*67 + 64;
      const float* r1 = W1 + (size_t)(cg*4 + 1)*67 + 64;
      const float* r2 = W1 + (size_t)(cg*4 + 2)*67 + 64;
      const float* r3 = W1 + (size_t)(cg*4 + 3)*67 + 64;
      float4 o;
      o.x = r0[0]*s0 + r0[1]*s1 + r0[2]*s2;
      o.y = r1[0]*s0 + r1[1]*s1 + r1[2]*s2;
      o.z = r2[0]*s0 + r2[1]*s1 + r2[2]*s2;
      o.w = r3[0]*s0 + r3[1]*s1 + r3[2]*s2;
      *(float4*)(V + (size_t)m*64 + cg*4) = o;
    }
    return;
  }
  if (blockIdx.x >= 1024) {          // W2 fragment image
    const int gg = (blockIdx.x - 1024) * 256 + t;
    if (gg < 1024) {
      const int g = gg >> 6, lane = gg & 63;
      const int q = lane >> 4, lr = lane & 15;
      const int kt = g >> 3, ot = g & 7;
      #pragma unroll
      for (int j = 0; j < 4; ++j)
        *(unsigned int*)&W2F[gg*8 + 2*j] =
            pk2f(W2[(ot*16 + lr)*64 + kt*32 + q*8 + 2*j],
                 W2[(ot*16 + lr)*64 + kt*32 + q*8 + 2*j + 1]);
    }
    return;
  }
  // ---- U-pack with LDS-transposed x/pos loads ----
  __shared__ float sx[67][65];
  const int n0 = blockIdx.x * 64;
  #pragma unroll
  for (int i = 0; i < 4; ++i) {
    const int lin = i*256 + t, r = lin >> 4, c4 = (lin & 15) * 4;
    const float4 v = *(const float4*)&x[(size_t)r * NPTS + n0 + c4];
    *(float4*)&sx[r][c4] = v;
  }
  if (t < 48) {
    const int lin = 1024 + t, r = lin >> 4, c4 = (lin & 15) * 4;
    const float4 v = *(const float4*)&pos[(size_t)(r - 64) * NPTS + n0 + c4];
    *(float4*)&sx[r][c4] = v;
  }

  const int lane = t & 63, w = t >> 6, quad = lane >> 4, lr = lane & 15;
  const int col = w * 16 + lr;
  const int n = n0 + col;

  bf16x8 wa[2][4], wt[4];
  #pragma unroll
  for (int kt = 0; kt < 2; ++kt)
    #pragma unroll
    for (int nt = 0; nt < 4; ++nt) {
      const float* r = W1 + (size_t)(nt*16 + lr)*67 + kt*32 + quad*8;
      const float4 a = *(const float4*)r;
      const float4 b = *(const float4*)(r + 4);
      union { unsigned int d[4]; bf16x8 v; } mk;
      mk.d[0] = pk2f(a.x, a.y); mk.d[1] = pk2f(a.z, a.w);
      mk.d[2] = pk2f(b.x, b.y); mk.d[3] = pk2f(b.z, b.w);
      wa[kt][nt] = mk.v;
    }
  #pragma unroll
  for (int nt = 0; nt < 4; ++nt) {
    union { unsigned int d[4]; bf16x8 v; } mk;
    mk.d[0] = 0u; mk.d[1] = 0u; mk.d[2] = 0u; mk.d[3] = 0u;
    if (quad == 0) {
      const float* r = W1 + (size_t)(nt*16 + lr)*67 + 64;
      mk.d[0] = pk2f(r[0], r[1]);
      mk.d[1] = (unsigned int)f2bf(r[2]);
    }
    wt[nt] = mk.v;
  }

  __syncthreads();

  const f32x4 fz = {0.f, 0.f, 0.f, 0.f};
  f32x4 acc[4] = {fz, fz, fz, fz};
  #pragma unroll
  for (int kt = 0; kt < 2; ++kt) {
    const int c0 = kt*32 + quad*8;
    union { unsigned int d[4]; bf16x8 v; } mk;
    #pragma unroll
    for (int i = 0; i < 4; ++i)
      mk.d[i] = pk2f(sx[c0 + 2*i][col], sx[c0 + 2*i + 1][col]);
    #pragma unroll
    for (int nt = 0; nt < 4; ++nt)
      acc[nt] = MFMA32(wa[kt][nt], mk.v, acc[nt]);
  }
  {
    union { unsigned int d[4]; bf16x8 v; } mk;
    mk.d[0] = pk2f(sx[64][col], sx[65][col]);
    mk.d[1] = (unsigned int)f2bf(sx[66][col]);
    mk.d[2] = 0u; mk.d[3] = 0u;
    #pragma unroll
    for (int nt = 0; nt < 4; ++nt)
      acc[nt] = MFMA32(wt[nt], mk.v, acc[nt]);
  }
  #pragma unroll
  for (int nt = 0; nt < 4; ++nt) {
    const float4 bb = *(const float4*)(b1 + nt*16 + quad*4);
    uint2 d;
    d.x = pk2f(acc[nt][0] + bb.x, acc[nt][1] + bb.y);
    d.y = pk2f(acc[nt][2] + bb.z, acc[nt][3] + bb.w);
    *(uint2*)(U + (size_t)n * 64 + nt*16 + quad*4) = d;
  }
}

// ---- main v7: LOOPED (small I-footprint), W2F in regs, idx/gather dbuf,
//      cndmask-select output accumulation, float2 stores ----
__global__ __launch_bounds__(256, 3) void pointnet_reg7(
    const unsigned short* __restrict__ U,    // [N][64] bf16
    const float* __restrict__ V,             // [M][64] fp32
    const unsigned short* __restrict__ W2F,
    const float* __restrict__ b2,
    const int* __restrict__ indices,         // [M][16]
    float* __restrict__ out) {               // [128][M]
  __shared__ float sv[32][68];
  const int t = threadIdx.x;
  const int lane = t & 63, w = t >> 6, quad = lane >> 4, lr = lane & 15;
  const int mbase = blockIdx.x * 32;
  const int wbase = mbase + w * 8;

  // V stage (wave-private rows, no barrier)
  const int vrow = w*8 + (lane >> 3), vcol = (lane & 7) * 8;
  const float* vg = &V[(size_t)(mbase + vrow) * 64 + vcol];
  const float4 va0 = *(const float4*)(vg);
  const float4 va1 = *(const float4*)(vg + 4);

  // idx prefetch for pt0, pt1
  int idx0 = indices[(wbase + 0)*16 + lr];
  int idx1 = indices[(wbase + 1)*16 + lr];

  // W2F hoisted to registers (L1-hot; 64 VGPR, read-only across the loop)
  bf16x8 wf[16];
  #pragma unroll
  for (int k8 = 0; k8 < 16; ++k8) wf[k8] = ((const bf16x8*)W2F)[k8*64 + lane];

  *(float4*)&sv[vrow][vcol]     = va0;
  *(float4*)&sv[vrow][vcol + 4] = va1;

  // gather pt0
  uint4 urA0, urA1, urB0, urB1;
  { const size_t rb = (size_t)idx0 * 64;
    urA0 = *(const uint4*)(U + rb + quad*8);
    urA1 = *(const uint4*)(U + rb + 32 + quad*8); }

  float vstA[8], vstB[8];
  #pragma unroll
  for (int ot = 0; ot < 8; ++ot) { vstA[ot] = 0.f; vstB[ot] = 0.f; }

  const f32x4 fz = {0.f, 0.f, 0.f, 0.f};

#define PN_COMPUTE(PT, UR0, UR1)                                            \
  {                                                                         \
    const float* vr = &sv[w*8 + (PT)][quad*8];                              \
    const f32x4 v0 = *(const f32x4*)(vr);                                   \
    const f32x4 v1 = *(const f32x4*)(vr + 4);                               \
    const f32x4 v2 = *(const f32x4*)(vr + 32);                              \
    const f32x4 v3 = *(const f32x4*)(vr + 36);                              \
    const float vv[16] = {v0[0],v0[1],v0[2],v0[3], v1[0],v1[1],v1[2],v1[3], \
                          v2[0],v2[1],v2[2],v2[3], v3[0],v3[1],v3[2],v3[3]};\
    bf16x8 ah0, ah1;                                                        \
    {                                                                       \
      const unsigned int uu[4] = {(UR0).x,(UR0).y,(UR0).z,(UR0).w};         \
      union { unsigned int d[4]; bf16x8 v; } mk;                            \
      _Pragma("unroll")                                                     \
      for (int i = 0; i < 4; ++i) {                                         \
        const float lo = bflo(uu[i]) - vv[2*i];                             \
        const float hi = bfhi(uu[i]) - vv[2*i+1];                           \
        mk.d[i] = pk2f(fmaxf(lo, 0.f), fmaxf(hi, 0.f));                     \
      }                                                                     \
      ah0 = mk.v;                                                           \
    }                                                                       \
    {                                                                       \
      const unsigned int uu[4] = {(UR1).x,(UR1).y,(UR1).z,(UR1).w};         \
      union { unsigned int d[4]; bf16x8 v; } mk;                            \
      _Pragma("unroll")                                                     \
      for (int i = 0; i < 4; ++i) {                                         \
        const float lo = bflo(uu[i]) - vv[8+2*i];                           \
        const float hi = bfhi(uu[i]) - vv[8+2*i+1];                         \
        mk.d[i] = pk2f(fmaxf(lo, 0.f), fmaxf(hi, 0.f));                     \
      }                                                                     \
      ah1 = mk.v;                                                           \
    }                                                                       \
    const bool eA = ((PT) == 2*quad);                                       \
    const bool eB = ((PT) == 2*quad + 1);                                   \
    _Pragma("unroll")                                                       \
    for (int ot = 0; ot < 8; ++ot) {                                        \
      f32x4 a2 = MFMA32(ah0, wf[ot], fz);                                   \
      a2 = MFMA32(ah1, wf[8+ot], a2);                                       \
      float q = red4(a2);                                                   \
      q = fmaxf(q, swz16(q));                                               \
      q = fmaxf(q, __shfl_xor(q, 32));                                      \
      vstA[ot] = eA ? q : vstA[ot];                                         \
      vstB[ot] = eB ? q : vstB[ot];                                         \
    }                                                                       \
  }

  #pragma unroll 1
  for (int pp = 0; pp < 4; ++pp) {
    const int ptE = 2*pp, ptO = 2*pp + 1;
    // prefetch pt=ptO gathers (cover under E-compute)
    { const size_t rb = (size_t)idx1 * 64;
      urB0 = *(const uint4*)(U + rb + quad*8);
      urB1 = *(const uint4*)(U + rb + 32 + quad*8); }
    // prefetch idx for ptE+2 (clamped; last-iter value unused)
    { int nx = ptE + 2; nx = (nx > 7) ? 0 : nx;
      idx0 = indices[(wbase + nx)*16 + lr]; }
    PN_COMPUTE(ptE, urA0, urA1)
    // prefetch pt=ptE+2 gathers (cover under O-compute)
    { const size_t rb = (size_t)idx0 * 64;
      urA0 = *(const uint4*)(U + rb + quad*8);
      urA1 = *(const uint4*)(U + rb + 32 + quad*8); }
    { int nx = ptO + 2; nx = (nx > 7) ? 0 : nx;
      idx1 = indices[(wbase + nx)*16 + lr]; }
    PN_COMPUTE(ptO, urB0, urB1)
  }
#undef PN_COMPUTE

  #pragma unroll
  for (int ot = 0; ot < 8; ++ot) {
    const int o = ot*16 + lr;
    const float bb = b2[o];
    float2 st; st.x = vstA[ot] + bb; st.y = vstB[ot] + bb;
    *(float2*)&out[(size_t)o * MPTS + wbase + 2*quad] = st;
  }
}

// ---- main v1 (middle path if workspace too small for V) ----
__global__ __launch_bounds__(256, 3) void pointnet_reg(
    const unsigned short* __restrict__ U,
    const float* __restrict__ sup,
    const float* __restrict__ W1,
    const unsigned short* __restrict__ W2F,
    const float* __restrict__ b2,
    const int* __restrict__ indices,
    float* __restrict__ out) {
  const int t = threadIdx.x;
  const int lane = t & 63, w = t >> 6, quad = lane >> 4, lr = lane & 15;
  const int wbase = blockIdx.x * 32 + w * 8;

  int idx[8];
  #pragma unroll
  for (int pt = 0; pt < 8; ++pt) idx[pt] = indices[(wbase + pt)*16 + lr];

  uint4 ur[8][2];
  #pragma unroll
  for (int pt = 0; pt < 8; ++pt)
    #pragma unroll
    for (int kt = 0; kt < 2; ++kt)
      ur[pt][kt] = *(const uint4*)(U + (size_t)idx[pt]*64 + kt*32 + quad*8);

  bf16x8 ah[8][2];
  #pragma unroll
  for (int kt = 0; kt < 2; ++kt) {
    float w1p[8][3];
    #pragma unroll
    for (int j = 0; j < 8; ++j) {
      const float* r = W1 + (size_t)(kt*32 + quad*8 + j)*67 + 64;
      w1p[j][0] = r[0]; w1p[j][1] = r[1]; w1p[j][2] = r[2];
    }
    #pragma unroll
    for (int pt = 0; pt < 8; ++pt) {
      const float s0 = sup[wbase + pt];
      const float s1 = sup[MPTS + wbase + pt];
      const float s2 = sup[2*MPTS + wbase + pt];
      const unsigned int uu[4] = {ur[pt][kt].x, ur[pt][kt].y, ur[pt][kt].z, ur[pt][kt].w};
      union { unsigned int d[4]; bf16x8 v; } mk;
      #pragma unroll
      for (int i = 0; i < 4; ++i) {
        const float vl = w1p[2*i][0]*s0 + w1p[2*i][1]*s1 + w1p[2*i][2]*s2;
        const float vh = w1p[2*i+1][0]*s0 + w1p[2*i+1][1]*s1 + w1p[2*i+1][2]*s2;
        const float hl = fmaxf(bflo(uu[i]) - vl, 0.f);
        const float hh = fmaxf(bfhi(uu[i]) - vh, 0.f);
        mk.d[i] = pk2f(hl, hh);
      }
      ah[pt][kt] = mk.v;
    }
  }

  const f32x4 fz = {0.f, 0.f, 0.f, 0.f};
  #pragma unroll
  for (int ot = 0; ot < 8; ++ot) {
    const bf16x8 wb0 = ((const bf16x8*)W2F)[(0*8 + ot)*64 + lane];
    const bf16x8 wb1 = ((const bf16x8*)W2F)[(1*8 + ot)*64 + lane];
    float vm[8];
    #pragma unroll
    for (int pt = 0; pt < 8; ++pt) {
      f32x4 a2 = MFMA32(ah[pt][0], wb0, fz);
      a2 = MFMA32(ah[pt][1], wb1, a2);
      float v = fmaxf(fmaxf(a2[0], a2[1]), fmaxf(a2[2], a2[3]));
      v = fmaxf(v, __shfl_xor(v, 16));
      v = fmaxf(v, __shfl_xor(v, 32));
      vm[pt] = v;
    }
    const int o = ot*16 + lr;
    const float bb = b2[o];
    const float va = (quad & 1) ? ((quad & 2) ? vm[3] : vm[1])
                                : ((quad & 2) ? vm[2] : vm[0]);
    const float vb = (quad & 1) ? ((quad & 2) ? vm[7] : vm[5])
                                : ((quad & 2) ? vm[6] : vm[4]);
    out[(size_t)o * MPTS + wbase + quad] = va + bb;
    out[(size_t)o * MPTS + wbase + 4 + quad] = vb + bb;
  }
}

// ---- fallback (ws too small): direct fp32 kernel, known-correct ----
__global__ __launch_bounds__(256) void pointnet_fallback(
    const float* __restrict__ x, const float* __restrict__ pos,
    const float* __restrict__ sup,
    const float* __restrict__ W1, const float* __restrict__ b1,
    const float* __restrict__ W2, const float* __restrict__ b2,
    const int* __restrict__ indices, float* __restrict__ out) {
  __shared__ float sfeat[16][68];
  __shared__ float shid[16][64];
  __shared__ float smax[4][128];
  __shared__ int sidx[16];
  const int t = threadIdx.x;
  const int m = blockIdx.x;
  if (t < 16) sidx[t] = indices[m*16 + t];
  const float sup0 = sup[m], sup1 = sup[MPTS + m], sup2 = sup[2*MPTS + m];
  __syncthreads();
  for (int u = t; u < 16*17; u += 256) {
    const int k = u / 17, c4 = (u - k*17) * 4;
    const int idx = sidx[k];
    float4 wv;
    if (c4 < 64) {
      wv.x = x[(size_t)(c4+0)*NPTS + idx]; wv.y = x[(size_t)(c4+1)*NPTS + idx];
      wv.z = x[(size_t)(c4+2)*NPTS + idx]; wv.w = x[(size_t)(c4+3)*NPTS + idx];
    } else {
      wv.x = pos[idx] - sup0; wv.y = pos[NPTS + idx] - sup1;
      wv.z = pos[2*NPTS + idx] - sup2; wv.w = 0.f;
    }
    *(float4*)&sfeat[k][c4] = wv;
  }
  const int h = t & 63, kg = t >> 6;
  float w1r[68];
  #pragma unroll
  for (int c = 0; c < 67; ++c) w1r[c] = W1[h*67 + c];
  w1r[67] = 0.f;
  const float bias1 = b1[h];
  __syncthreads();
  #pragma unroll
  for (int j = 0; j < 4; ++j) {
    const int k = kg*4 + j;
    float a = bias1;
    const float4* rr = (const float4*)sfeat[k];
    #pragma unroll
    for (int qq = 0; qq < 17; ++qq) {
      const float4 v = rr[qq];
      a += w1r[qq*4+0]*v.x + w1r[qq*4+1]*v.y + w1r[qq*4+2]*v.z + w1r[qq*4+3]*v.w;
    }
    shid[k][h] = fmaxf(a, 0.f);
  }
  const int ow = t & 63;
  float w2a[64], w2b[64];
  #pragma unroll
  for (int hh = 0; hh < 64; ++hh) { w2a[hh] = W2[ow*64 + hh]; w2b[hh] = W2[(ow+64)*64 + hh]; }
  __syncthreads();
  float mxa = -3.0e38f, mxb = -3.0e38f;
  #pragma unroll
  for (int j = 0; j < 4; ++j) {
    const int k = kg*4 + j;
    const float4* hr = (const float4*)shid[k];
    float pa = 0.f, pb = 0.f;
    #pragma unroll
    for (int qq = 0; qq < 16; ++qq) {
      const float4 v = hr[qq];
      pa += w2a[qq*4+0]*v.x + w2a[qq*4+1]*v.y + w2a[qq*4+2]*v.z + w2a[qq*4+3]*v.w;
      pb += w2b[qq*4+0]*v.x + w2b[qq*4+1]*v.y + w2b[qq*4+2]*v.z + w2b[qq*4+3]*v.w;
    }
    mxa = fmaxf(mxa, pa); mxb = fmaxf(mxb, pb);
  }
  smax[kg][ow] = mxa; smax[kg][64 + ow] = mxb;
  __syncthreads();
  if (t < 128) {
    out[(size_t)t * MPTS + m] =
        fmaxf(fmaxf(smax[0][t], smax[1][t]), fmaxf(smax[2][t], smax[3][t])) + b2[t];
  }
}

extern "C" void kernel_launch(void* const* d_in, const int* in_sizes, int n_in,
                              void* d_out, int out_size, void* d_ws, size_t ws_size,
                              hipStream_t stream) {
  const float* x   = (const float*)d_in[0];
  const float* pos = (const float*)d_in[1];
  const float* sup = (const float*)d_in[2];
  const float* W1  = (const float*)d_in[3];
  const float* b1  = (const float*)d_in[4];
  const float* W2  = (const float*)d_in[5];
  const float* b2  = (const float*)d_in[6];
  const int* indices = (const int*)d_in[7];
  float* out = (float*)d_out;

  const size_t U_BYTES   = (size_t)NPTS * 64 * 2;     // 8,388,608
  const size_t W2F_BYTES = 16 * 64 * 8 * 2;           // 16,384
  const size_t V_BYTES   = (size_t)MPTS * 64 * 4;     // 16,777,216
  if (ws_size >= U_BYTES + W2F_BYTES + V_BYTES) {
    unsigned short* U   = (unsigned short*)d_ws;
    unsigned short* W2F = (unsigned short*)((char*)d_ws + U_BYTES);
    float* V            = (float*)((char*)d_ws + U_BYTES + W2F_BYTES);
    pack_all<<<1284, 256, 0, stream>>>(x, pos, sup, W1, b1, W2, U, W2F, V);
    pointnet_reg7<<<MPTS/32, 256, 0, stream>>>(U, V, W2F, b2, indices, out);
  } else if (ws_size >= U_BYTES + W2F_BYTES) {
    unsigned short* U   = (unsigned short*)d_ws;
    unsigned short* W2F = (unsigned short*)((char*)d_ws + U_BYTES);
    pack_all<<<1028, 256, 0, stream>>>(x, pos, sup, W1, b1, W2, U, W2F, nullptr);
    pointnet_reg<<<MPTS/32, 256, 0, stream>>>(U, sup, W1, W2F, b2, indices, out);
  } else {
    pointnet_fallback<<<MPTS, 256, 0, stream>>>(x, pos, sup, W1, b1, W2, b2, indices, out);
  }
}